// Round 20
// baseline (88.518 us; speedup 1.0000x reference)
//
#include <hip/hip_runtime.h>
#include <stdint.h>
#include <stddef.h>

typedef short bf16x8 __attribute__((ext_vector_type(8)));
typedef float f32x4 __attribute__((ext_vector_type(4)));
typedef int i32x4 __attribute__((ext_vector_type(4)));

#define AS1 __attribute__((address_space(1)))
#define AS3 __attribute__((address_space(3)))

// log2(e)/8: folded into K-projection so QK^T MFMA output feeds v_exp_f32 directly
#define KSCALE 0.18033688011112042f
#define MFMA16(A, B, C) __builtin_amdgcn_mfma_f32_16x16x32_bf16(A, B, C, 0, 0, 0)

__device__ __forceinline__ unsigned short f2bf(float f) {
    union { float f; uint32_t u; } v; v.f = f;
    return (unsigned short)((v.u + 0x7fffu + ((v.u >> 16) & 1u)) >> 16);
}

// ---------- f32 -> bf16 convert (4 elems/thread) ----------
__global__ void cvt_f32_bf16(const float* __restrict__ in, unsigned short* __restrict__ out, int n4) {
    int i = blockIdx.x * blockDim.x + threadIdx.x;
    if (i >= n4) return;
    float4 v = reinterpret_cast<const float4*>(in)[i];
    ushort4 o;
    o.x = f2bf(v.x); o.y = f2bf(v.y); o.z = f2bf(v.z); o.w = f2bf(v.w);
    reinterpret_cast<ushort4*>(out)[i] = o;
}

// ---------- 512x512 transpose f32 -> bf16 for all 3 weights ----------
__global__ void wtrans3(const float* __restrict__ Wk, const float* __restrict__ Wv,
                        const float* __restrict__ Wo,
                        unsigned short* __restrict__ WkT, unsigned short* __restrict__ WvT,
                        unsigned short* __restrict__ WoT) {
    __shared__ float tile[32][33];
    const float* W = (blockIdx.z == 0) ? Wk : (blockIdx.z == 1) ? Wv : Wo;
    unsigned short* WT = (blockIdx.z == 0) ? WkT : (blockIdx.z == 1) ? WvT : WoT;
    int bk = blockIdx.x * 32, bn = blockIdx.y * 32;
    int tx = threadIdx.x, ty = threadIdx.y;
#pragma unroll
    for (int r = 0; r < 32; r += 8)
        tile[ty + r][tx] = W[(size_t)(bk + ty + r) * 512 + bn + tx];
    __syncthreads();
#pragma unroll
    for (int r = 0; r < 32; r += 8)
        WT[(size_t)(bn + ty + r) * 512 + bk + tx] = f2bf(tile[tx][ty + r]);
}

// ---------- GEMM: C[M=8192][N=512] = A * BT^T + bias; 64x128 tile (r17 config, unchanged) ----------
template<int EPI>
__global__ __launch_bounds__(256, 2) void gemm64(const unsigned short* __restrict__ A,
                                                 const unsigned short* __restrict__ BT,
                                                 const float* __restrict__ bias,
                                                 void* __restrict__ outp) {
    __shared__ unsigned short lA[64 * 64];
    __shared__ unsigned short lB[128 * 64];
    const int tid = threadIdx.x;
    const int tile_n = blockIdx.x * 128;
    const int tile_m = blockIdx.y * 64;
    const int wid = tid >> 6, lane = tid & 63;
    const int wm = (wid >> 1) * 32, wn = (wid & 1) * 64;
    const int l16 = lane & 15, lg = lane >> 4;

    f32x4 acc[2][4];
#pragma unroll
    for (int i = 0; i < 2; ++i)
#pragma unroll
        for (int j = 0; j < 4; ++j)
            acc[i][j] = (f32x4){0.f, 0.f, 0.f, 0.f};

    const int r0 = tid >> 3;
    const int cr = tid & 7;

    for (int kt = 0; kt < 512; kt += 64) {
#pragma unroll
        for (int i = 0; i < 2; ++i) {
            int r = r0 + i * 32;
            int crs = cr ^ (r & 7);
            __builtin_amdgcn_global_load_lds((const AS1 void*)(A + (size_t)(tile_m + r) * 512 + kt + crs * 8),
                                             (AS3 void*)(&lA[(i * 256 + tid) * 8]), 16, 0, 0);
        }
#pragma unroll
        for (int i = 0; i < 4; ++i) {
            int r = r0 + i * 32;
            int crs = cr ^ (r & 7);
            __builtin_amdgcn_global_load_lds((const AS1 void*)(BT + (size_t)(tile_n + r) * 512 + kt + crs * 8),
                                             (AS3 void*)(&lB[(i * 256 + tid) * 8]), 16, 0, 0);
        }
        __syncthreads();
#pragma unroll
        for (int ks = 0; ks < 2; ++ks) {
            bf16x8 af[2], bfr[4];
#pragma unroll
            for (int f = 0; f < 2; ++f) {
                int ra = wm + f * 16 + l16;
                af[f] = *reinterpret_cast<const bf16x8*>(
                    reinterpret_cast<const char*>(lA) + ra * 128 + (((ks * 4 + lg) ^ (ra & 7)) << 4));
            }
#pragma unroll
            for (int f = 0; f < 4; ++f) {
                int rb = wn + f * 16 + l16;
                bfr[f] = *reinterpret_cast<const bf16x8*>(
                    reinterpret_cast<const char*>(lB) + rb * 128 + (((ks * 4 + lg) ^ (rb & 7)) << 4));
            }
#pragma unroll
            for (int fm = 0; fm < 2; ++fm)
#pragma unroll
                for (int fn = 0; fn < 4; ++fn)
                    acc[fm][fn] = MFMA16(af[fm], bfr[fn], acc[fm][fn]);
        }
        __syncthreads();
    }

#pragma unroll
    for (int fm = 0; fm < 2; ++fm)
#pragma unroll
        for (int fn = 0; fn < 4; ++fn) {
            int gm0 = tile_m + wm + fm * 16 + lg * 4;
            int gn = tile_n + wn + fn * 16 + l16;
            float bs = bias[gn];
#pragma unroll
            for (int r = 0; r < 4; ++r) {
                float v = acc[fm][fn][r] + bs;
                int m = gm0 + r;
                if (EPI == 0) {
                    v *= KSCALE;
                    int b = m >> 11, s = m & 2047, h = gn >> 6, d = gn & 63;
                    ((unsigned short*)outp)[(((size_t)(b * 8 + h) * 2048 + s) << 6) + d] = f2bf(v);
                } else if (EPI == 1) {
                    int b = m >> 11, s = m & 2047, h = gn >> 6, d = gn & 63;
                    ((unsigned short*)outp)[(((size_t)(b * 8 + h) * 64 + d) << 11) + s] = f2bf(v);
                } else {
                    ((float*)outp)[(size_t)m * 512 + gn] = v;
                }
            }
        }
}

// ---------- causal flash attention: 2 q-tiles per wave, 2-wave blocks ----------
// attn is bound by REDUNDANT LDS reads (r18 analysis: 67584 wave-phases x 16KB
// at 85 B/cy effective b128 throughput = ~21us = observed). Fix: each wave owns
// 32 q-rows as tiles A/B; every K/V fragment read feeds MFMAs for BOTH tiles ->
// LDS read bytes per unit work HALVED. Unlike r12 (which lost): blocks stay
// 64 rows (2 waves), grid stays 32x32=1024 = 4 blocks/CU, longest block stays
// 32 phases -> critical path and occupancy preserved. Double-buffered LDS
// (32KB), 8 staging loads/thread at 128 threads (same verified key perm).
// Fixed-zero-max softmax + MFMA row-sum denominator (r17, verified).
__global__ __launch_bounds__(128, 2) void attn_f(const unsigned short* __restrict__ xq,
                                                 const unsigned short* __restrict__ kg,
                                                 const unsigned short* __restrict__ vT,
                                                 unsigned short* __restrict__ ob) {
    __shared__ unsigned short lsK[2][4096];   // [64 keys(perm)][64 d], 8KB per buf
    __shared__ unsigned short lsV[2][4096];   // V^T [64 d][64 keys], 8KB per buf

    const int tid = threadIdx.x;              // 0..127
    const int lane = tid & 63;
    const int w = tid >> 6;                   // 0..1
    const int l16 = lane & 15, lg = lane >> 4;
    const int bh = blockIdx.x, b = bh >> 3, h = bh & 7;
    const int qblk = 31 - blockIdx.y;         // heavy first (LPT)
    const int qlo = qblk * 64 + w * 32;       // wave rows [qlo, qlo+32): tile A low 16, B high 16
    const int qA = qlo + l16;

    const unsigned short* Kb = kg + (size_t)bh * (2048 * 64);
    const unsigned short* Vb = vT + (size_t)bh * (64 * 2048);

    const unsigned short* qp = xq + ((size_t)(b * 2048 + qlo + l16) * 512) + h * 64 + lg * 8;
    bf16x8 qfA0 = *(const bf16x8*)qp;
    bf16x8 qfA1 = *(const bf16x8*)(qp + 32);
    bf16x8 qfB0 = *(const bf16x8*)(qp + 16 * 512);
    bf16x8 qfB1 = *(const bf16x8*)(qp + 16 * 512 + 32);

    const bf16x8 vones = {(short)0x3F80, (short)0x3F80, (short)0x3F80, (short)0x3F80,
                          (short)0x3F80, (short)0x3F80, (short)0x3F80, (short)0x3F80};

    f32x4 oA[4], oB[4];
    f32x4 osA = (f32x4){0.f, 0.f, 0.f, 0.f}, osB = (f32x4){0.f, 0.f, 0.f, 0.f};
#pragma unroll
    for (int i = 0; i < 4; ++i) { oA[i] = (f32x4){0.f, 0.f, 0.f, 0.f}; oB[i] = (f32x4){0.f, 0.f, 0.f, 0.f}; }

    const int nph = qblk + 1;
    const int myntA = ((qlo + 15) >> 6) + 1;
    const int myntB = ((qlo + 31) >> 6) + 1;   // == nph for w=1

    // staging: 128 threads x 8 x 16B loads (4 K rows-groups + 4 V row-groups).
    // LDS row mapping identical to r17: K row r holds key 32*(r>>5)+8*((r>>2)&3)+(r&3)+4*((r>>4)&1),
    // chunk c holds global chunk c^(r&7). V row r = d (identity), same chunk swizzle.
    const int s0 = tid >> 3;                  // 0..15
    const int scs = (tid & 7) ^ (s0 & 7);
    const int sk0 = 8 * (s0 >> 2) + (s0 & 3);

#define GLL(SRC, DST) __builtin_amdgcn_global_load_lds((const AS1 void*)(SRC), (AS3 void*)(DST), 16, 0, 0)
#define STAGE(B, PH) { \
        const int kv0_ = (PH) << 6; \
        GLL(Kb + (size_t)(kv0_ + sk0     ) * 64 + scs * 8, &lsK[B][(size_t)tid * 8]); \
        GLL(Kb + (size_t)(kv0_ + sk0 + 4 ) * 64 + scs * 8, &lsK[B][1024 + (size_t)tid * 8]); \
        GLL(Kb + (size_t)(kv0_ + sk0 + 32) * 64 + scs * 8, &lsK[B][2048 + (size_t)tid * 8]); \
        GLL(Kb + (size_t)(kv0_ + sk0 + 36) * 64 + scs * 8, &lsK[B][3072 + (size_t)tid * 8]); \
        GLL(Vb + (size_t)(s0     ) * 2048 + kv0_ + scs * 8, &lsV[B][(size_t)tid * 8]); \
        GLL(Vb + (size_t)(s0 + 16) * 2048 + kv0_ + scs * 8, &lsV[B][1024 + (size_t)tid * 8]); \
        GLL(Vb + (size_t)(s0 + 32) * 2048 + kv0_ + scs * 8, &lsV[B][2048 + (size_t)tid * 8]); \
        GLL(Vb + (size_t)(s0 + 48) * 2048 + kv0_ + scs * 8, &lsV[B][3072 + (size_t)tid * 8]); }

// read group-G K frags ONCE, MFMA into both tiles (A guarded by actA)
#define QK2(G, SA0, SA1, SB0, SB1) { \
            const char* r0p = KS + (32 * (G) + l16) * 128; \
            const char* r1p = r0p + 16 * 128; \
            bf16x8 k00 = *(const bf16x8*)(r0p + ((lg ^ sw) << 4)); \
            bf16x8 k01 = *(const bf16x8*)(r0p + (((lg + 4) ^ sw) << 4)); \
            bf16x8 k10 = *(const bf16x8*)(r1p + ((lg ^ sw) << 4)); \
            bf16x8 k11 = *(const bf16x8*)(r1p + (((lg + 4) ^ sw) << 4)); \
            __builtin_amdgcn_s_setprio(1); \
            SB0 = MFMA16(k00, qfB0, SB0); SB0 = MFMA16(k01, qfB1, SB0); \
            SB1 = MFMA16(k10, qfB0, SB1); SB1 = MFMA16(k11, qfB1, SB1); \
            if (actA) { \
                SA0 = MFMA16(k00, qfA0, SA0); SA0 = MFMA16(k01, qfA1, SA0); \
                SA1 = MFMA16(k10, qfA0, SA1); SA1 = MFMA16(k11, qfA1, SA1); \
            } \
            __builtin_amdgcn_s_setprio(0); }

// mask + exp2 for a 32-key group of one tile
#define MEXP(G, S0, S1, P0, P1, QROW, QMIN) { \
            if (kvb + 32 * (G) + 31 > (QMIN)) { \
                _Pragma("unroll") \
                for (int r = 0; r < 4; ++r) { \
                    int kidx = kvb + 32 * (G) + 8 * lg + r; \
                    P0[r] = __builtin_amdgcn_exp2f(kidx > (QROW) ? -1e30f : S0[r]); \
                    P1[r] = __builtin_amdgcn_exp2f(kidx + 4 > (QROW) ? -1e30f : S1[r]); \
                } \
            } else { \
                _Pragma("unroll") \
                for (int r = 0; r < 4; ++r) { \
                    P0[r] = __builtin_amdgcn_exp2f(S0[r]); \
                    P1[r] = __builtin_amdgcn_exp2f(S1[r]); \
                } \
            } }

#define CVT8(P0, P1, P2, P3, PU0, PU1) { \
            uint32_t u0, u1, u2, u3, u4, u5, u6, u7; \
            asm("v_cvt_pk_bf16_f32 %0, %1, %2" : "=v"(u0) : "v"(P0[0]), "v"(P0[1])); \
            asm("v_cvt_pk_bf16_f32 %0, %1, %2" : "=v"(u1) : "v"(P0[2]), "v"(P0[3])); \
            asm("v_cvt_pk_bf16_f32 %0, %1, %2" : "=v"(u2) : "v"(P1[0]), "v"(P1[1])); \
            asm("v_cvt_pk_bf16_f32 %0, %1, %2" : "=v"(u3) : "v"(P1[2]), "v"(P1[3])); \
            asm("v_cvt_pk_bf16_f32 %0, %1, %2" : "=v"(u4) : "v"(P2[0]), "v"(P2[1])); \
            asm("v_cvt_pk_bf16_f32 %0, %1, %2" : "=v"(u5) : "v"(P2[2]), "v"(P2[3])); \
            asm("v_cvt_pk_bf16_f32 %0, %1, %2" : "=v"(u6) : "v"(P3[0]), "v"(P3[1])); \
            asm("v_cvt_pk_bf16_f32 %0, %1, %2" : "=v"(u7) : "v"(P3[2]), "v"(P3[3])); \
            PU0.i = (i32x4){(int)u0, (int)u1, (int)u2, (int)u3}; \
            PU1.i = (i32x4){(int)u4, (int)u5, (int)u6, (int)u7}; }

    const int sw = l16 & 7;
    STAGE(0, 0);
    for (int ph = 0; ph < nph; ++ph) {
        const int cur = ph & 1;
        if (ph + 1 < nph) {
            STAGE(cur ^ 1, ph + 1);
            asm volatile("s_waitcnt vmcnt(8)" ::: "memory");   // next stage's 8 loads stay in flight
        } else {
            asm volatile("s_waitcnt vmcnt(0)" ::: "memory");
        }
        __builtin_amdgcn_s_barrier();
        asm volatile("" ::: "memory");
        const bool actA = ph < myntA;
        if (ph < myntB) {
            const char* KS = (const char*)lsK[cur];
            const char* VS = (const char*)lsV[cur];
            const int kvb = ph << 6;
            f32x4 sa0 = (f32x4){0.f,0.f,0.f,0.f}, sa1 = sa0, sa2 = sa0, sa3 = sa0;
            f32x4 sb0 = sa0, sb1 = sa0, sb2 = sa0, sb3 = sa0;
            QK2(0, sa0, sa1, sb0, sb1)
            QK2(1, sa2, sa3, sb2, sb3)
            // tile B (rows qA+16)
            float pb0[4], pb1[4], pb2[4], pb3[4];
            MEXP(0, sb0, sb1, pb0, pb1, qA + 16, qlo + 16)
            MEXP(1, sb2, sb3, pb2, pb3, qA + 16, qlo + 16)
            union { i32x4 i; bf16x8 h; } puB0, puB1;
            CVT8(pb0, pb1, pb2, pb3, puB0, puB1)
            union { i32x4 i; bf16x8 h; } puA0, puA1;
            if (actA) {
                float pa0[4], pa1[4], pa2[4], pa3[4];
                MEXP(0, sa0, sa1, pa0, pa1, qA, qlo)
                MEXP(1, sa2, sa3, pa2, pa3, qA, qlo)
                CVT8(pa0, pa1, pa2, pa3, puA0, puA1)
            }
            __builtin_amdgcn_s_setprio(1);
            osB = MFMA16(puB0.h, vones, osB);
            osB = MFMA16(puB1.h, vones, osB);
            if (actA) {
                osA = MFMA16(puA0.h, vones, osA);
                osA = MFMA16(puA1.h, vones, osA);
            }
            // PV: V frags read ONCE, feed both tiles
#pragma unroll
            for (int nb = 0; nb < 4; ++nb) {
                const char* vr = VS + (nb * 16 + l16) * 128;
                bf16x8 vf0 = *(const bf16x8*)(vr + ((lg ^ sw) << 4));
                bf16x8 vf1 = *(const bf16x8*)(vr + (((lg + 4) ^ sw) << 4));
                oB[nb] = MFMA16(puB0.h, vf0, oB[nb]);
                oB[nb] = MFMA16(puB1.h, vf1, oB[nb]);
                if (actA) {
                    oA[nb] = MFMA16(puA0.h, vf0, oA[nb]);
                    oA[nb] = MFMA16(puA1.h, vf1, oA[nb]);
                }
            }
            __builtin_amdgcn_s_setprio(0);
        }
        asm volatile("" ::: "memory");
        __builtin_amdgcn_s_barrier();
    }
#undef STAGE
#undef GLL
#undef QK2
#undef MEXP
#undef CVT8

    float linvA[4], linvB[4];
#pragma unroll
    for (int r = 0; r < 4; ++r) {
        linvA[r] = 1.f / osA[r];
        linvB[r] = 1.f / osB[r];
    }
#pragma unroll
    for (int nb = 0; nb < 4; ++nb)
#pragma unroll
        for (int r = 0; r < 4; ++r) {
            int s = qlo + 4 * lg + r;
            size_t base = (size_t)(b * 2048 + s) * 512 + h * 64 + nb * 16 + l16;
            ob[base] = f2bf(oA[nb][r] * linvA[r]);
            ob[base + 16 * 512] = f2bf(oB[nb][r] * linvB[r]);
        }
}

extern "C" void kernel_launch(void* const* d_in, const int* in_sizes, int n_in,
                              void* d_out, int out_size, void* d_ws, size_t ws_size,
                              hipStream_t stream) {
    const float* x  = (const float*)d_in[0];
    const float* Wk = (const float*)d_in[1];
    const float* bk = (const float*)d_in[2];
    const float* Wv = (const float*)d_in[3];
    const float* bv = (const float*)d_in[4];
    const float* Wo = (const float*)d_in[5];
    const float* bo = (const float*)d_in[6];

    char* ws = (char*)d_ws;
    unsigned short* xb   = (unsigned short*)(ws);                    // 8 MB  [8192][512] bf16
    unsigned short* kbuf = (unsigned short*)(ws + (8ull << 20));     // 8 MB  [B][H][S][64] (pre-scaled)
    unsigned short* vTb  = (unsigned short*)(ws + (16ull << 20));    // 8 MB  [B][H][64][S]
    unsigned short* obuf = (unsigned short*)(ws + (24ull << 20));    // 8 MB  [8192][512]
    unsigned short* WkT  = (unsigned short*)(ws + (32ull << 20));    // 512 KB
    unsigned short* WvT  = (unsigned short*)(ws + (33ull << 20));    // 512 KB
    unsigned short* WoT  = (unsigned short*)(ws + (34ull << 20));    // 512 KB

    cvt_f32_bf16<<<4096, 256, 0, stream>>>(x, xb, 1048576);
    wtrans3<<<dim3(16, 16, 3), dim3(32, 8), 0, stream>>>(Wk, Wv, Wo, WkT, WvT, WoT);

    dim3 gg(4, 128);
    gemm64<0><<<gg, 256, 0, stream>>>(xb, WkT, bk, kbuf);
    gemm64<1><<<gg, 256, 0, stream>>>(xb, WvT, bv, vTb);

    attn_f<<<dim3(32, 32), 128, 0, stream>>>(xb, kbuf, vTb, obuf);

    gemm64<2><<<gg, 256, 0, stream>>>(obuf, WoT, bo, (float*)d_out);
}

// Round 24
// 77.187 us; speedup vs baseline: 1.1468x; 1.1468x over previous
//
#include <hip/hip_runtime.h>
#include <stdint.h>
#include <stddef.h>

typedef short bf16x8 __attribute__((ext_vector_type(8)));
typedef float f32x4 __attribute__((ext_vector_type(4)));
typedef int i32x4 __attribute__((ext_vector_type(4)));

#define AS1 __attribute__((address_space(1)))
#define AS3 __attribute__((address_space(3)))

// log2(e)/8: folded into K-projection so QK^T MFMA output feeds v_exp_f32 directly
#define KSCALE 0.18033688011112042f
#define MFMA16(A, B, C) __builtin_amdgcn_mfma_f32_16x16x32_bf16(A, B, C, 0, 0, 0)

__device__ __forceinline__ unsigned short f2bf(float f) {
    union { float f; uint32_t u; } v; v.f = f;
    return (unsigned short)((v.u + 0x7fffu + ((v.u >> 16) & 1u)) >> 16);
}

// ---------- f32 -> bf16 convert (4 elems/thread) ----------
__global__ void cvt_f32_bf16(const float* __restrict__ in, unsigned short* __restrict__ out, int n4) {
    int i = blockIdx.x * blockDim.x + threadIdx.x;
    if (i >= n4) return;
    float4 v = reinterpret_cast<const float4*>(in)[i];
    ushort4 o;
    o.x = f2bf(v.x); o.y = f2bf(v.y); o.z = f2bf(v.z); o.w = f2bf(v.w);
    reinterpret_cast<ushort4*>(out)[i] = o;
}

// ---------- 512x512 transpose f32 -> bf16 for all 3 weights ----------
__global__ void wtrans3(const float* __restrict__ Wk, const float* __restrict__ Wv,
                        const float* __restrict__ Wo,
                        unsigned short* __restrict__ WkT, unsigned short* __restrict__ WvT,
                        unsigned short* __restrict__ WoT) {
    __shared__ float tile[32][33];
    const float* W = (blockIdx.z == 0) ? Wk : (blockIdx.z == 1) ? Wv : Wo;
    unsigned short* WT = (blockIdx.z == 0) ? WkT : (blockIdx.z == 1) ? WvT : WoT;
    int bk = blockIdx.x * 32, bn = blockIdx.y * 32;
    int tx = threadIdx.x, ty = threadIdx.y;
#pragma unroll
    for (int r = 0; r < 32; r += 8)
        tile[ty + r][tx] = W[(size_t)(bk + ty + r) * 512 + bn + tx];
    __syncthreads();
#pragma unroll
    for (int r = 0; r < 32; r += 8)
        WT[(size_t)(bn + ty + r) * 512 + bk + tx] = f2bf(tile[tx][ty + r]);
}

// ---------- GEMM: C[M=8192][N=512] = A * BT^T + bias; 64x128 tile (r13 config) ----------
// grid (4, 128) = 512 blocks = 2/CU. 4 waves: each 32x64 output.
// EPI 0: K-proj -> kb [B][H][S][64] bf16, scaled by KSCALE
// EPI 1: V-proj -> vT [B][H][64][S] bf16
// EPI 2: O-proj -> out [M][512] f32
template<int EPI>
__global__ __launch_bounds__(256, 2) void gemm64(const unsigned short* __restrict__ A,
                                                 const unsigned short* __restrict__ BT,
                                                 const float* __restrict__ bias,
                                                 void* __restrict__ outp) {
    __shared__ unsigned short lA[64 * 64];
    __shared__ unsigned short lB[128 * 64];
    const int tid = threadIdx.x;
    const int tile_n = blockIdx.x * 128;
    const int tile_m = blockIdx.y * 64;
    const int wid = tid >> 6, lane = tid & 63;
    const int wm = (wid >> 1) * 32, wn = (wid & 1) * 64;
    const int l16 = lane & 15, lg = lane >> 4;

    f32x4 acc[2][4];
#pragma unroll
    for (int i = 0; i < 2; ++i)
#pragma unroll
        for (int j = 0; j < 4; ++j)
            acc[i][j] = (f32x4){0.f, 0.f, 0.f, 0.f};

    const int r0 = tid >> 3;
    const int cr = tid & 7;

    for (int kt = 0; kt < 512; kt += 64) {
#pragma unroll
        for (int i = 0; i < 2; ++i) {
            int r = r0 + i * 32;
            int crs = cr ^ (r & 7);
            __builtin_amdgcn_global_load_lds((const AS1 void*)(A + (size_t)(tile_m + r) * 512 + kt + crs * 8),
                                             (AS3 void*)(&lA[(i * 256 + tid) * 8]), 16, 0, 0);
        }
#pragma unroll
        for (int i = 0; i < 4; ++i) {
            int r = r0 + i * 32;
            int crs = cr ^ (r & 7);
            __builtin_amdgcn_global_load_lds((const AS1 void*)(BT + (size_t)(tile_n + r) * 512 + kt + crs * 8),
                                             (AS3 void*)(&lB[(i * 256 + tid) * 8]), 16, 0, 0);
        }
        __syncthreads();
#pragma unroll
        for (int ks = 0; ks < 2; ++ks) {
            bf16x8 af[2], bfr[4];
#pragma unroll
            for (int f = 0; f < 2; ++f) {
                int ra = wm + f * 16 + l16;
                af[f] = *reinterpret_cast<const bf16x8*>(
                    reinterpret_cast<const char*>(lA) + ra * 128 + (((ks * 4 + lg) ^ (ra & 7)) << 4));
            }
#pragma unroll
            for (int f = 0; f < 4; ++f) {
                int rb = wn + f * 16 + l16;
                bfr[f] = *reinterpret_cast<const bf16x8*>(
                    reinterpret_cast<const char*>(lB) + rb * 128 + (((ks * 4 + lg) ^ (rb & 7)) << 4));
            }
#pragma unroll
            for (int fm = 0; fm < 2; ++fm)
#pragma unroll
                for (int fn = 0; fn < 4; ++fn)
                    acc[fm][fn] = MFMA16(af[fm], bfr[fn], acc[fm][fn]);
        }
        __syncthreads();
    }

#pragma unroll
    for (int fm = 0; fm < 2; ++fm)
#pragma unroll
        for (int fn = 0; fn < 4; ++fn) {
            int gm0 = tile_m + wm + fm * 16 + lg * 4;
            int gn = tile_n + wn + fn * 16 + l16;
            float bs = bias[gn];
#pragma unroll
            for (int r = 0; r < 4; ++r) {
                float v = acc[fm][fn][r] + bs;
                int m = gm0 + r;
                if (EPI == 0) {
                    v *= KSCALE;
                    int b = m >> 11, s = m & 2047, h = gn >> 6, d = gn & 63;
                    ((unsigned short*)outp)[(((size_t)(b * 8 + h) * 2048 + s) << 6) + d] = f2bf(v);
                } else if (EPI == 1) {
                    int b = m >> 11, s = m & 2047, h = gn >> 6, d = gn & 63;
                    ((unsigned short*)outp)[(((size_t)(b * 8 + h) * 64 + d) << 11) + s] = f2bf(v);
                } else {
                    ((float*)outp)[(size_t)m * 512 + gn] = v;
                }
            }
        }
}

// ---------- causal flash attention: fixed-zero-max + triple-buffer + MFMA row-sum ----------
// (r17, verified best at 77.5us total.) Softmax denominator via MFMA against an
// all-ones B fragment: osum accumulates exact row sums of P with the SAME row
// mapping as o -> no per-phase add tree, no serial lsum chain, no cross-lane
// shuffles. Fixed-zero-max softmax is numerically safe (|s*scale| <~ 6).
// Triple-buffered LDS hides 2 phases of load latency; counted vmcnt keeps
// loads in flight across barriers. 4 waves x 16 q-rows; heavy-first LPT grid.
// NOTE (r20): do NOT reduce waves/block — 2-wave blocks halved residency and
// cost 1.9x despite halving LDS reads; attn is latency-bound, not LDS-bound.
__global__ __launch_bounds__(256, 3) void attn_f(const unsigned short* __restrict__ xq,
                                                 const unsigned short* __restrict__ kg,
                                                 const unsigned short* __restrict__ vT,
                                                 unsigned short* __restrict__ ob) {
    __shared__ unsigned short lsK[3][4096];   // [64 keys(perm)][64 d], 8KB per buf
    __shared__ unsigned short lsV[3][4096];   // V^T [64 d][64 keys], 8KB per buf

    const int tid = threadIdx.x;
    const int lane = tid & 63;
    const int w = tid >> 6;
    const int l16 = lane & 15, lg = lane >> 4;
    const int bh = blockIdx.x, b = bh >> 3, h = bh & 7;
    const int qblk = 31 - blockIdx.y;         // heavy first (LPT)
    const int qlo = qblk * 64 + w * 16;
    const int q = qlo + l16;

    const unsigned short* Kb = kg + (size_t)bh * (2048 * 64);
    const unsigned short* Vb = vT + (size_t)bh * (64 * 2048);

    const unsigned short* qp = xq + ((size_t)(b * 2048 + qlo + l16) * 512) + h * 64 + lg * 8;
    bf16x8 qf0 = *(const bf16x8*)qp;
    bf16x8 qf1 = *(const bf16x8*)(qp + 32);

    const bf16x8 vones = {(short)0x3F80, (short)0x3F80, (short)0x3F80, (short)0x3F80,
                          (short)0x3F80, (short)0x3F80, (short)0x3F80, (short)0x3F80};

    f32x4 o[4];
    f32x4 osum = (f32x4){0.f, 0.f, 0.f, 0.f};
#pragma unroll
    for (int i = 0; i < 4; ++i) o[i] = (f32x4){0.f, 0.f, 0.f, 0.f};

    const int nph = qblk + 1;                 // same for all 4 waves

    const int srow = tid >> 3;
    const int scs = (tid & 7) ^ (srow & 7);
    const int skey = 8 * ((srow >> 2) & 3) + (srow & 3) + 4 * (srow >> 4);

#define STAGE(B, PH) { \
        const int kv0_ = (PH) << 6; \
        __builtin_amdgcn_global_load_lds((const AS1 void*)(Kb + (size_t)(kv0_ + skey) * 64 + scs * 8), \
            (AS3 void*)(&lsK[B][(size_t)tid * 8]), 16, 0, 0); \
        __builtin_amdgcn_global_load_lds((const AS1 void*)(Kb + (size_t)(kv0_ + 32 + skey) * 64 + scs * 8), \
            (AS3 void*)(&lsK[B][(size_t)(256 + tid) * 8]), 16, 0, 0); \
        __builtin_amdgcn_global_load_lds((const AS1 void*)(Vb + (size_t)srow * 2048 + kv0_ + scs * 8), \
            (AS3 void*)(&lsV[B][(size_t)tid * 8]), 16, 0, 0); \
        __builtin_amdgcn_global_load_lds((const AS1 void*)(Vb + (size_t)(srow + 32) * 2048 + kv0_ + scs * 8), \
            (AS3 void*)(&lsV[B][(size_t)(256 + tid) * 8]), 16, 0, 0); }

#define QKGRP(G, PA, PB, KS, KVB) { \
            const char* r0p = (KS) + (32 * (G) + l16) * 128; \
            const char* r1p = r0p + 16 * 128; \
            bf16x8 k00 = *(const bf16x8*)(r0p + ((lg ^ sw) << 4)); \
            bf16x8 k01 = *(const bf16x8*)(r0p + (((lg + 4) ^ sw) << 4)); \
            bf16x8 k10 = *(const bf16x8*)(r1p + ((lg ^ sw) << 4)); \
            bf16x8 k11 = *(const bf16x8*)(r1p + (((lg + 4) ^ sw) << 4)); \
            f32x4 sA = (f32x4){0.f,0.f,0.f,0.f}, sB = (f32x4){0.f,0.f,0.f,0.f}; \
            __builtin_amdgcn_s_setprio(1); \
            sA = MFMA16(k00, qf0, sA); \
            sA = MFMA16(k01, qf1, sA); \
            sB = MFMA16(k10, qf0, sB); \
            sB = MFMA16(k11, qf1, sB); \
            __builtin_amdgcn_s_setprio(0); \
            if ((KVB) + 32 * (G) + 31 > qlo) { \
                _Pragma("unroll") \
                for (int r = 0; r < 4; ++r) { \
                    int kidx = (KVB) + 32 * (G) + 8 * lg + r; \
                    PA[r] = __builtin_amdgcn_exp2f(kidx > q ? -1e30f : sA[r]); \
                    PB[r] = __builtin_amdgcn_exp2f(kidx + 4 > q ? -1e30f : sB[r]); \
                } \
            } else { \
                _Pragma("unroll") \
                for (int r = 0; r < 4; ++r) { \
                    PA[r] = __builtin_amdgcn_exp2f(sA[r]); \
                    PB[r] = __builtin_amdgcn_exp2f(sB[r]); \
                } \
            } }

    const int sw = l16 & 7;
    STAGE(0, 0);
    if (nph > 1) STAGE(1, 1);
    int cur = 0, st = 2;
    for (int ph = 0; ph < nph; ++ph) {
        if (ph + 2 < nph) {
            STAGE(st, ph + 2);
            asm volatile("s_waitcnt vmcnt(8)" ::: "memory");   // stages ph+1, ph+2 in flight
        } else if (ph + 1 < nph) {
            asm volatile("s_waitcnt vmcnt(4)" ::: "memory");   // stage ph+1 in flight
        } else {
            asm volatile("s_waitcnt vmcnt(0)" ::: "memory");
        }
        __builtin_amdgcn_s_barrier();
        asm volatile("" ::: "memory");
        {
            const char* KS = (const char*)lsK[cur];
            const char* VS = (const char*)lsV[cur];
            const int kvb = ph << 6;
            float pA0[4], pB0[4], pA1[4], pB1[4];
            QKGRP(0, pA0, pB0, KS, kvb)
            QKGRP(1, pA1, pB1, KS, kvb)
            uint32_t u0, u1, u2, u3, u4, u5, u6, u7;
            asm("v_cvt_pk_bf16_f32 %0, %1, %2" : "=v"(u0) : "v"(pA0[0]), "v"(pA0[1]));
            asm("v_cvt_pk_bf16_f32 %0, %1, %2" : "=v"(u1) : "v"(pA0[2]), "v"(pA0[3]));
            asm("v_cvt_pk_bf16_f32 %0, %1, %2" : "=v"(u2) : "v"(pB0[0]), "v"(pB0[1]));
            asm("v_cvt_pk_bf16_f32 %0, %1, %2" : "=v"(u3) : "v"(pB0[2]), "v"(pB0[3]));
            asm("v_cvt_pk_bf16_f32 %0, %1, %2" : "=v"(u4) : "v"(pA1[0]), "v"(pA1[1]));
            asm("v_cvt_pk_bf16_f32 %0, %1, %2" : "=v"(u5) : "v"(pA1[2]), "v"(pA1[3]));
            asm("v_cvt_pk_bf16_f32 %0, %1, %2" : "=v"(u6) : "v"(pB1[0]), "v"(pB1[1]));
            asm("v_cvt_pk_bf16_f32 %0, %1, %2" : "=v"(u7) : "v"(pB1[2]), "v"(pB1[3]));
            union { i32x4 i; bf16x8 h; } pu0, pu1;
            pu0.i = (i32x4){(int)u0, (int)u1, (int)u2, (int)u3};
            pu1.i = (i32x4){(int)u4, (int)u5, (int)u6, (int)u7};
            __builtin_amdgcn_s_setprio(1);
            // row-sum via MFMA: D[i][j] = sum_k P[i][k] * 1 -> denominator,
            // same row mapping as o (replicated across l16)
            osum = MFMA16(pu0.h, vones, osum);
            osum = MFMA16(pu1.h, vones, osum);
#pragma unroll
            for (int nb = 0; nb < 4; ++nb) {
                const char* vr = VS + (nb * 16 + l16) * 128;
                bf16x8 vf0 = *(const bf16x8*)(vr + ((lg ^ sw) << 4));
                bf16x8 vf1 = *(const bf16x8*)(vr + (((lg + 4) ^ sw) << 4));
                o[nb] = MFMA16(pu0.h, vf0, o[nb]);
                o[nb] = MFMA16(pu1.h, vf1, o[nb]);
            }
            __builtin_amdgcn_s_setprio(0);
        }
        asm volatile("" ::: "memory");
        __builtin_amdgcn_s_barrier();
        cur = (cur == 2) ? 0 : cur + 1;
        st = (st == 2) ? 0 : st + 1;
    }
#undef STAGE
#undef QKGRP

    float linv[4];
#pragma unroll
    for (int r = 0; r < 4; ++r)
        linv[r] = 1.f / osum[r];
#pragma unroll
    for (int nb = 0; nb < 4; ++nb)
#pragma unroll
        for (int r = 0; r < 4; ++r) {
            int s = qlo + 4 * lg + r;
            ob[(size_t)(b * 2048 + s) * 512 + h * 64 + nb * 16 + l16] = f2bf(o[nb][r] * linv[r]);
        }
}

extern "C" void kernel_launch(void* const* d_in, const int* in_sizes, int n_in,
                              void* d_out, int out_size, void* d_ws, size_t ws_size,
                              hipStream_t stream) {
    const float* x  = (const float*)d_in[0];
    const float* Wk = (const float*)d_in[1];
    const float* bk = (const float*)d_in[2];
    const float* Wv = (const float*)d_in[3];
    const float* bv = (const float*)d_in[4];
    const float* Wo = (const float*)d_in[5];
    const float* bo = (const float*)d_in[6];

    char* ws = (char*)d_ws;
    unsigned short* xb   = (unsigned short*)(ws);                    // 8 MB  [8192][512] bf16
    unsigned short* kbuf = (unsigned short*)(ws + (8ull << 20));     // 8 MB  [B][H][S][64] (pre-scaled)
    unsigned short* vTb  = (unsigned short*)(ws + (16ull << 20));    // 8 MB  [B][H][64][S]
    unsigned short* obuf = (unsigned short*)(ws + (24ull << 20));    // 8 MB  [8192][512]
    unsigned short* WkT  = (unsigned short*)(ws + (32ull << 20));    // 512 KB
    unsigned short* WvT  = (unsigned short*)(ws + (33ull << 20));    // 512 KB
    unsigned short* WoT  = (unsigned short*)(ws + (34ull << 20));    // 512 KB

    cvt_f32_bf16<<<4096, 256, 0, stream>>>(x, xb, 1048576);
    wtrans3<<<dim3(16, 16, 3), dim3(32, 8), 0, stream>>>(Wk, Wv, Wo, WkT, WvT, WoT);

    dim3 gg(4, 128);
    gemm64<0><<<gg, 256, 0, stream>>>(xb, WkT, bk, kbuf);
    gemm64<1><<<gg, 256, 0, stream>>>(xb, WvT, bv, vTb);

    attn_f<<<dim3(32, 32), 256, 0, stream>>>(xb, kbuf, vTb, obuf);

    gemm64<2><<<gg, 256, 0, stream>>>(obuf, WoT, bo, (float*)d_out);
}